// Round 6
// baseline (127.173 us; speedup 1.0000x reference)
//
#include <hip/hip_runtime.h>
#include <hip/hip_bf16.h>
#include <math.h>

#define NB 4
#define NT 4096
#define NC 512
#define NH 64
#define KVBLK 64
#define LDK 72      // padded LDS row stride (bf16 elems) = 144 B
#define MASKV (-1e30f)
#define CHT 4       // kv tiles per chunk (256 kv)

typedef __attribute__((ext_vector_type(8))) short bf16x8;
typedef __attribute__((ext_vector_type(4))) float f32x4;

__device__ inline unsigned short f2bf(float f) {
    __hip_bfloat16 h = __float2bfloat16(f);
    return *reinterpret_cast<unsigned short*>(&h);
}
__device__ inline float bf2f(unsigned int u16bits) {
    unsigned int u = u16bits << 16;
    return *reinterpret_cast<float*>(&u);
}

// ---------------- Kernel 0: pack W^T bf16 [192][512] ----------------
// Wq pre-scaled by log2(e)/sqrt(512): QK^T scores land in exp2 domain.
__global__ __launch_bounds__(256) void wconv(
    const float* __restrict__ Wk, const float* __restrict__ Wq,
    const float* __restrict__ Wv, unsigned short* __restrict__ Wt)
{
    int idx = blockIdx.x * 256 + threadIdx.x;   // 98304 = 512*192
    int n = idx % 192, c = idx / 192;
    int sel = n >> 6, h = n & 63;
    const float* W = (sel == 0) ? Wq : (sel == 1) ? Wk : Wv;
    float val = W[c * NH + h];
    if (sel == 0) val *= 0.063758715f;  // log2(e)/sqrt(512)
    Wt[n * NC + c] = f2bf(val);
}

// ---------------- Kernel 1: QKV projection as MFMA GEMM (BM=32) ----------------
// q,k row-major [b*t][h]; v TRANSPOSED vt[b][h][t].
__global__ __launch_bounds__(256) void qkv_gemm(
    const float* __restrict__ x, const unsigned short* __restrict__ Wt,
    unsigned short* __restrict__ q, unsigned short* __restrict__ k,
    unsigned short* __restrict__ vt)
{
    __shared__ unsigned short xa[32][LDK];
    __shared__ unsigned short wb[192][LDK];

    const int tid = threadIdx.x;
    const int w = tid >> 6, lane = tid & 63, l15 = lane & 15, g = lane >> 4;
    const size_t r0 = (size_t)blockIdx.x * 32;

    f32x4 acc[2][3];
    #pragma unroll
    for (int mt = 0; mt < 2; ++mt)
        #pragma unroll
        for (int nt = 0; nt < 3; ++nt) acc[mt][nt] = (f32x4){0.f,0.f,0.f,0.f};

    for (int c0 = 0; c0 < NC; c0 += 64) {
        __syncthreads();
        {
            int row = tid >> 3, f8 = tid & 7;
            const float* xp = x + (r0 + row) * NC + c0 + f8*8;
            float4 x0 = *reinterpret_cast<const float4*>(xp);
            float4 x1 = *reinterpret_cast<const float4*>(xp + 4);
            bf16x8 a8;
            a8[0]=f2bf(x0.x); a8[1]=f2bf(x0.y); a8[2]=f2bf(x0.z); a8[3]=f2bf(x0.w);
            a8[4]=f2bf(x1.x); a8[5]=f2bf(x1.y); a8[6]=f2bf(x1.z); a8[7]=f2bf(x1.w);
            *reinterpret_cast<bf16x8*>(&xa[row][f8*8]) = a8;
        }
        #pragma unroll
        for (int i = 0; i < 6; ++i) {
            int idx = tid + 256*i;
            int row = idx >> 3, f8 = idx & 7;
            bf16x8 w8 = *reinterpret_cast<const bf16x8*>(Wt + (size_t)row * NC + c0 + f8*8);
            *reinterpret_cast<bf16x8*>(&wb[row][f8*8]) = w8;
        }
        __syncthreads();

        #pragma unroll
        for (int kk = 0; kk < 2; ++kk) {
            bf16x8 a[2], bfr[3];
            #pragma unroll
            for (int mt = 0; mt < 2; ++mt)
                a[mt] = *reinterpret_cast<const bf16x8*>(&xa[16*mt + l15][32*kk + 8*g]);
            #pragma unroll
            for (int nt = 0; nt < 3; ++nt)
                bfr[nt] = *reinterpret_cast<const bf16x8*>(&wb[48*w + 16*nt + l15][32*kk + 8*g]);
            __builtin_amdgcn_s_setprio(1);
            #pragma unroll
            for (int mt = 0; mt < 2; ++mt)
                #pragma unroll
                for (int nt = 0; nt < 3; ++nt)
                    acc[mt][nt] = __builtin_amdgcn_mfma_f32_16x16x32_bf16(a[mt], bfr[nt], acc[mt][nt], 0, 0, 0);
            __builtin_amdgcn_s_setprio(0);
        }
    }

    #pragma unroll
    for (int mt = 0; mt < 2; ++mt)
        #pragma unroll
        for (int nt = 0; nt < 3; ++nt) {
            int ncol = 48*w + 16*nt + l15;
            int sel = ncol >> 6, h = ncol & 63;
            if (sel < 2) {
                unsigned short* dst = (sel == 0) ? q : k;
                #pragma unroll
                for (int r = 0; r < 4; ++r)
                    dst[(r0 + 16*mt + 4*g + r) * NH + h] = f2bf(acc[mt][nt][r]);
            } else {
                int bb = (int)(r0 >> 12);
                int trow = ((int)r0 & (NT-1)) + 16*mt + 4*g;
                unsigned int lo = (unsigned int)f2bf(acc[mt][nt][0]) | ((unsigned int)f2bf(acc[mt][nt][1]) << 16);
                unsigned int hi = (unsigned int)f2bf(acc[mt][nt][2]) | ((unsigned int)f2bf(acc[mt][nt][3]) << 16);
                *reinterpret_cast<uint2*>(&vt[((size_t)bb*NH + h)*NT + trow]) = make_uint2(lo, hi);
            }
        }
}

// ---------------- Kernel 2: barrier-free split-KV MFMA flash attention ----------------
// 256-thread blocks = 4 INDEPENDENT waves (no __syncthreads). Wave handles
// (32 q-rows, 256-kv chunk): linear = blockIdx.x*4 + w; ch = linear&15,
// qt = 127 - (linear>>4) (heavy-first). K and V^T fragments direct
// global->register (L2-hot); swapped S^T = K·Q^T; per-wave LDS P roundtrip.
__global__ __launch_bounds__(256, 4) void attn_part(
    const unsigned short* __restrict__ qg,
    const unsigned short* __restrict__ kg,
    const unsigned short* __restrict__ vtg,
    float* __restrict__ out,
    unsigned short* __restrict__ O_part,   // bf16 partials
    float* __restrict__ ML_part)
{
    __shared__ unsigned short p_lds[4][32][LDK];   // 18.4 KB, per-wave

    const int w    = threadIdx.x >> 6;
    const int lane = threadIdx.x & 63;
    const int linear = blockIdx.x * 4 + w;      // [0, 2048)
    const int ch = linear & 15;
    const int qt = 127 - (linear >> 4);
    const int nT = (qt >> 1) + 1;               // kv tiles of 64 needed
    if (CHT * ch >= nT) return;
    const int b  = blockIdx.y;

    const int l15  = lane & 15;
    const int g    = lane >> 4;
    const int q0 = qt * 32;
    const size_t base = (size_t)b * NT * NH;

    bf16x8 qf[2][2];
    #pragma unroll
    for (int qc = 0; qc < 2; ++qc) {
        const unsigned short* qp = qg + base + (size_t)(q0 + 16*qc + l15) * NH + 8*g;
        qf[qc][0] = *reinterpret_cast<const bf16x8*>(qp);
        qf[qc][1] = *reinterpret_cast<const bf16x8*>(qp + 32);
    }

    f32x4 ot[4][2];
    #pragma unroll
    for (int dt = 0; dt < 4; ++dt)
        #pragma unroll
        for (int qc = 0; qc < 2; ++qc) ot[dt][qc] = (f32x4){0.f,0.f,0.f,0.f};
    float m0 = MASKV, m1 = MASKV, l0 = 0.f, l1 = 0.f;

    const int tBeg = CHT * ch;
    const int tEnd = min(CHT * (ch + 1), nT);

    for (int it = tBeg; it < tEnd; ++it) {
        const int s0 = it * KVBLK;

        const unsigned short* kbase = kg + base + (size_t)(s0 + l15) * NH + 8*g;
        bf16x8 ka[4][2];
        #pragma unroll
        for (int t = 0; t < 4; ++t)
            #pragma unroll
            for (int kk = 0; kk < 2; ++kk)
                ka[t][kk] = *reinterpret_cast<const bf16x8*>(kbase + t*16*NH + kk*32);

        f32x4 s[4][2];
        __builtin_amdgcn_s_setprio(1);
        #pragma unroll
        for (int t = 0; t < 4; ++t)
            #pragma unroll
            for (int qc = 0; qc < 2; ++qc) {
                s[t][qc] = __builtin_amdgcn_mfma_f32_16x16x32_bf16(ka[t][0], qf[qc][0], (f32x4){0.f,0.f,0.f,0.f}, 0, 0, 0);
                s[t][qc] = __builtin_amdgcn_mfma_f32_16x16x32_bf16(ka[t][1], qf[qc][1], s[t][qc], 0, 0, 0);
            }
        __builtin_amdgcn_s_setprio(0);

        // V^T fragments issued now, in flight under softmax
        const unsigned short* vbase = vtg + ((size_t)b*NH + l15)*NT + s0 + 8*g;
        bf16x8 vf[4][2];
        #pragma unroll
        for (int dt = 0; dt < 4; ++dt)
            #pragma unroll
            for (int kk = 0; kk < 2; ++kk)
                vf[dt][kk] = *reinterpret_cast<const bf16x8*>(vbase + (size_t)dt*16*NT + kk*32);

        if (s0 + KVBLK - 1 > q0) {
            #pragma unroll
            for (int t = 0; t < 4; ++t)
                #pragma unroll
                for (int qc = 0; qc < 2; ++qc) {
                    const int qr = q0 + 16*qc + l15;
                    #pragma unroll
                    for (int r = 0; r < 4; ++r)
                        if (s0 + 16*t + 4*g + r > qr) s[t][qc][r] = MASKV;
                }
        }

        float pm0 = MASKV, pm1 = MASKV;
        #pragma unroll
        for (int t = 0; t < 4; ++t)
            #pragma unroll
            for (int r = 0; r < 4; ++r) {
                pm0 = fmaxf(pm0, s[t][0][r]);
                pm1 = fmaxf(pm1, s[t][1][r]);
            }
        pm0 = fmaxf(pm0, __shfl_xor(pm0, 16)); pm0 = fmaxf(pm0, __shfl_xor(pm0, 32));
        pm1 = fmaxf(pm1, __shfl_xor(pm1, 16)); pm1 = fmaxf(pm1, __shfl_xor(pm1, 32));

        // defer-max: rescale only when max grew by > 8 (exp2 domain; P <= 256)
        if (!__all(pm0 <= m0 + 8.f && pm1 <= m1 + 8.f)) {
            float mn0 = fmaxf(m0, pm0), mn1 = fmaxf(m1, pm1);
            float c0 = exp2f(m0 - mn0), c1 = exp2f(m1 - mn1);
            l0 *= c0; l1 *= c1;
            #pragma unroll
            for (int dt = 0; dt < 4; ++dt)
                #pragma unroll
                for (int e = 0; e < 4; ++e) {
                    ot[dt][0][e] *= c0;
                    ot[dt][1][e] *= c1;
                }
            m0 = mn0; m1 = mn1;
        }

        float ps0 = 0.f, ps1 = 0.f;
        #pragma unroll
        for (int t = 0; t < 4; ++t)
            #pragma unroll
            for (int r = 0; r < 4; ++r) {
                float p0 = exp2f(s[t][0][r] - m0);
                float p1 = exp2f(s[t][1][r] - m1);
                s[t][0][r] = p0; s[t][1][r] = p1;
                ps0 += p0; ps1 += p1;
            }

        #pragma unroll
        for (int qc = 0; qc < 2; ++qc)
            #pragma unroll
            for (int t = 0; t < 4; ++t) {
                unsigned int w0 = (unsigned int)f2bf(s[t][qc][0]) | ((unsigned int)f2bf(s[t][qc][1]) << 16);
                unsigned int w1 = (unsigned int)f2bf(s[t][qc][2]) | ((unsigned int)f2bf(s[t][qc][3]) << 16);
                *reinterpret_cast<unsigned int*>(&p_lds[w][16*qc + l15][16*t + 4*g])     = w0;
                *reinterpret_cast<unsigned int*>(&p_lds[w][16*qc + l15][16*t + 4*g + 2]) = w1;
            }

        ps0 += __shfl_xor(ps0, 16); ps0 += __shfl_xor(ps0, 32);
        ps1 += __shfl_xor(ps1, 16); ps1 += __shfl_xor(ps1, 32);
        l0 += ps0; l1 += ps1;

        bf16x8 pf[2][2];
        #pragma unroll
        for (int qc = 0; qc < 2; ++qc)
            #pragma unroll
            for (int kk = 0; kk < 2; ++kk)
                pf[qc][kk] = *reinterpret_cast<const bf16x8*>(&p_lds[w][16*qc + l15][8*g + 32*kk]);
        __builtin_amdgcn_s_setprio(1);
        #pragma unroll
        for (int kk = 0; kk < 2; ++kk)
            #pragma unroll
            for (int dt = 0; dt < 4; ++dt)
                #pragma unroll
                for (int qc = 0; qc < 2; ++qc)
                    ot[dt][qc] = __builtin_amdgcn_mfma_f32_16x16x32_bf16(vf[dt][kk], pf[qc][kk], ot[dt][qc], 0, 0, 0);
        __builtin_amdgcn_s_setprio(0);
    }

    if (nT <= CHT) {
        const float inv0 = 1.f / l0, inv1 = 1.f / l1;
        #pragma unroll
        for (int qc = 0; qc < 2; ++qc) {
            float inv = qc ? inv1 : inv0;
            float* orow = out + base + (size_t)(q0 + 16*qc + l15) * NH;
            #pragma unroll
            for (int dt = 0; dt < 4; ++dt) {
                f32x4 o4;
                #pragma unroll
                for (int r = 0; r < 4; ++r) o4[r] = ot[dt][qc][r] * inv;
                *reinterpret_cast<f32x4*>(&orow[16*dt + 4*g]) = o4;
            }
        }
    } else {
        const int slot = ((b << 7 | qt) << 4) + ch;
        unsigned short* op = O_part + (size_t)slot * (32*NH);
        #pragma unroll
        for (int qc = 0; qc < 2; ++qc)
            #pragma unroll
            for (int dt = 0; dt < 4; ++dt) {
                unsigned int lo = (unsigned int)f2bf(ot[dt][qc][0]) | ((unsigned int)f2bf(ot[dt][qc][1]) << 16);
                unsigned int hi = (unsigned int)f2bf(ot[dt][qc][2]) | ((unsigned int)f2bf(ot[dt][qc][3]) << 16);
                *reinterpret_cast<uint2*>(&op[(size_t)(16*qc + l15) * NH + 16*dt + 4*g]) = make_uint2(lo, hi);
            }
        if (g == 0) {
            float* mlp = ML_part + (size_t)slot * 64;
            *reinterpret_cast<float2*>(&mlp[2*l15])        = make_float2(m0, l0);
            *reinterpret_cast<float2*>(&mlp[2*(16 + l15)]) = make_float2(m1, l1);
        }
    }
}

// ---------------- Kernel 3: merge split-KV partials (qt >= 8) ----------------
__global__ __launch_bounds__(256) void attn_merge(
    const unsigned short* __restrict__ O_part,
    const float* __restrict__ ML_part,
    float* __restrict__ out)
{
    const int qt = 8 + blockIdx.x;             // 8..127
    const int b  = blockIdx.y;
    const int nch = (((qt >> 1) + 1) + CHT - 1) / CHT;
    const int slot0 = (b << 7 | qt) << 4;
    const int row = threadIdx.x >> 3;          // 0..31
    const int dq  = (threadIdx.x & 7) * 8;     // 8 d's per thread

    float M = MASKV;
    for (int c = 0; c < nch; ++c)
        M = fmaxf(M, ML_part[(size_t)(slot0 + c) * 64 + 2*row]);

    float L = 0.f;
    float acc[8];
    #pragma unroll
    for (int j = 0; j < 8; ++j) acc[j] = 0.f;

    for (int c = 0; c < nch; ++c) {
        const float* mlp = &ML_part[(size_t)(slot0 + c) * 64 + 2*row];
        float wgt = exp2f(mlp[0] - M);
        L += wgt * mlp[1];
        const unsigned short* op = O_part + (size_t)(slot0 + c) * (32*NH) + (size_t)row * NH + dq;
        uint4 pk = *reinterpret_cast<const uint4*>(op);
        acc[0] = fmaf(wgt, bf2f(pk.x & 0xffff), acc[0]);
        acc[1] = fmaf(wgt, bf2f(pk.x >> 16),    acc[1]);
        acc[2] = fmaf(wgt, bf2f(pk.y & 0xffff), acc[2]);
        acc[3] = fmaf(wgt, bf2f(pk.y >> 16),    acc[3]);
        acc[4] = fmaf(wgt, bf2f(pk.z & 0xffff), acc[4]);
        acc[5] = fmaf(wgt, bf2f(pk.z >> 16),    acc[5]);
        acc[6] = fmaf(wgt, bf2f(pk.w & 0xffff), acc[6]);
        acc[7] = fmaf(wgt, bf2f(pk.w >> 16),    acc[7]);
    }

    const float inv = 1.f / L;
    float* orow = out + (size_t)b * NT * NH + (size_t)(qt * 32 + row) * NH + dq;
    #pragma unroll
    for (int j4 = 0; j4 < 2; ++j4) {
        float4 o4;
        o4.x = acc[4*j4+0] * inv;
        o4.y = acc[4*j4+1] * inv;
        o4.z = acc[4*j4+2] * inv;
        o4.w = acc[4*j4+3] * inv;
        *reinterpret_cast<float4*>(orow + 4*j4) = o4;
    }
}

extern "C" void kernel_launch(void* const* d_in, const int* in_sizes, int n_in,
                              void* d_out, int out_size, void* d_ws, size_t ws_size,
                              hipStream_t stream) {
    const float* x  = (const float*)d_in[0];
    const float* Wk = (const float*)d_in[1];
    const float* Wq = (const float*)d_in[2];
    const float* Wv = (const float*)d_in[3];
    float* out = (float*)d_out;

    const size_t n = (size_t)NB * NT * NH;              // 1,048,576
    unsigned short* qb = (unsigned short*)d_ws;         // 2 MB
    unsigned short* kb = qb + n;                        // 2 MB
    unsigned short* vt = kb + n;                        // 2 MB (vt[b][h][t])
    unsigned short* Wt = vt + n;                        // 196 KB
    unsigned short* O_part = Wt + 192 * NC;             // 8192 slots * 4 KB = 33.5 MB (bf16)
    float* ML_part = (float*)(O_part + (size_t)8192 * 32 * NH);  // 2 MB

    wconv<<<(192*NC)/256, 256, 0, stream>>>(Wk, Wq, Wv, Wt);
    qkv_gemm<<<(NB*NT)/32, 256, 0, stream>>>(x, Wt, qb, kb, vt);

    dim3 pgrid(512, NB);     // 2048 wave-chunks per batch, 4 waves/block
    attn_part<<<pgrid, 256, 0, stream>>>(qb, kb, vt, out, O_part, ML_part);
    dim3 mgrid(120, NB);
    attn_merge<<<mgrid, 256, 0, stream>>>(O_part, ML_part, out);
}